// Round 1
// 617.037 us; speedup vs baseline: 1.0222x; 1.0222x over previous
//
#include <hip/hip_runtime.h>
#include <hip/hip_bf16.h>

// ---------------------------------------------------------------------------
// SparseLinear: y = spmm(COO, x^T)^T + bias
// R4: 64x64 vectorized transposes (float4 loads, uint4/float4 stores),
//     spmm 4-deep gather pipeline with edge-group prefetch.
//     Numerics identical to R3 (same RNE rounding, same FMA order).
// ---------------------------------------------------------------------------

// x (rows, cols) fp32 -> out (cols, rows) bf16. 64x64 tile, block = 256.
__global__ __launch_bounds__(256) void transpose_bf16_v2(
        const float* __restrict__ in,
        __hip_bfloat16* __restrict__ out,
        int rows, int cols) {
    // [col_local][row_local]; row stride 72 ushorts = 144 B (odd multiple of
    // 16 B -> conflict-free uint4 reads in store phase)
    __shared__ __hip_bfloat16 T[64][72];
    const int t  = threadIdx.x;
    const int c0 = blockIdx.x * 64;   // over cols
    const int r0 = blockIdx.y * 64;   // over rows

    {   // load phase: float4 per lane; wave reads 4 rows x 256 B segments
        const int tx = t & 15, ty = t >> 4;
        const int c = c0 + tx * 4;
        for (int p = 0; p < 4; ++p) {
            const int rl = ty + p * 16;
            const int r = r0 + rl;
            float4 f = make_float4(0.f, 0.f, 0.f, 0.f);
            if (r < rows && c + 3 < cols) {
                f = *(const float4*)(in + (size_t)r * cols + c);
            } else if (r < rows) {
                const float* p0 = in + (size_t)r * cols;
                if (c + 0 < cols) f.x = p0[c + 0];
                if (c + 1 < cols) f.y = p0[c + 1];
                if (c + 2 < cols) f.z = p0[c + 2];
                if (c + 3 < cols) f.w = p0[c + 3];
            }
            T[tx * 4 + 0][rl] = __float2bfloat16(f.x);
            T[tx * 4 + 1][rl] = __float2bfloat16(f.y);
            T[tx * 4 + 2][rl] = __float2bfloat16(f.z);
            T[tx * 4 + 3][rl] = __float2bfloat16(f.w);
        }
    }
    __syncthreads();
    {   // store phase: uint4 = 8 bf16 per lane; 8 x 128 B segments per wave
        const int cl0 = t >> 3;   // 0..31
        const int rq  = t & 7;    // 0..7
        const int rl  = rq * 8;
        const int r   = r0 + rl;
        for (int q = 0; q < 2; ++q) {
            const int cl = q * 32 + cl0;
            const int c  = c0 + cl;
            if (c < cols) {
                if (r + 7 < rows) {
                    *(uint4*)(out + (size_t)c * rows + r) =
                        *(const uint4*)&T[cl][rl];
                } else {
                    for (int j = 0; j < 8 && r + j < rows; ++j)
                        out[(size_t)c * rows + r + j] = T[cl][rl + j];
                }
            }
        }
    }
}

// in (rows, cols) fp32 -> out (cols, rows) fp32. 64x64 tile, block = 256.
__global__ __launch_bounds__(256) void transpose32_v2(
        const float* __restrict__ in,
        float* __restrict__ out,
        int rows, int cols) {
    // row stride 68 floats = 272 B (odd multiple of 16 B)
    __shared__ float T[64][68];
    const int t  = threadIdx.x;
    const int c0 = blockIdx.x * 64;   // over cols
    const int r0 = blockIdx.y * 64;   // over rows

    {   // load: float4 per lane
        const int tx = t & 15, ty = t >> 4;
        const int c = c0 + tx * 4;
        for (int p = 0; p < 4; ++p) {
            const int rl = ty + p * 16;
            const int r = r0 + rl;
            float4 f = make_float4(0.f, 0.f, 0.f, 0.f);
            if (r < rows && c + 3 < cols) {
                f = *(const float4*)(in + (size_t)r * cols + c);
            } else if (r < rows) {
                const float* p0 = in + (size_t)r * cols;
                if (c + 0 < cols) f.x = p0[c + 0];
                if (c + 1 < cols) f.y = p0[c + 1];
                if (c + 2 < cols) f.z = p0[c + 2];
                if (c + 3 < cols) f.w = p0[c + 3];
            }
            T[tx * 4 + 0][rl] = f.x;
            T[tx * 4 + 1][rl] = f.y;
            T[tx * 4 + 2][rl] = f.z;
            T[tx * 4 + 3][rl] = f.w;
        }
    }
    __syncthreads();
    {   // store: float4 per lane; 4 x 256 B segments per wave
        const int rq  = t & 15;   // float4 over r
        const int cl0 = t >> 4;   // 0..15
        const int rl  = rq * 4;
        const int r   = r0 + rl;
        for (int p = 0; p < 4; ++p) {
            const int cl = p * 16 + cl0;
            const int c  = c0 + cl;
            if (c < cols) {
                if (r + 3 < rows) {
                    *(float4*)(out + (size_t)c * rows + r) =
                        *(const float4*)&T[cl][rl];
                } else {
                    for (int j = 0; j < 4 && r + j < rows; ++j)
                        out[(size_t)c * rows + r + j] = T[cl][rl + j];
                }
            }
        }
    }
}

__global__ void zero_i32_kernel(int* __restrict__ p, int n) {
    int i = blockIdx.x * blockDim.x + threadIdx.x;
    if (i < n) p[i] = 0;
}

__global__ void hist_kernel(const int* __restrict__ rows, int nnz,
                            int* __restrict__ counts) {
    int e = blockIdx.x * blockDim.x + threadIdx.x;
    if (e < nnz) atomicAdd(&counts[rows[e]], 1);
}

// ---- hierarchical exclusive scan of counts[0..n) into offsets[0..n] --------
#define SCAN_T 256
#define SCAN_CHUNK 2048

__global__ __launch_bounds__(SCAN_T) void scan1_kernel(
        const int* __restrict__ counts, int* __restrict__ offsets,
        int* __restrict__ bsum, int n) {
    __shared__ int sdata[SCAN_T];
    int t = threadIdx.x;
    int base_i = blockIdx.x * SCAN_CHUNK + t * 8;
    int vals[8];
    int tot = 0;
#pragma unroll
    for (int j = 0; j < 8; ++j) {
        int i = base_i + j;
        int v = (i < n) ? counts[i] : 0;
        tot += v;
        vals[j] = tot;
    }
    sdata[t] = tot;
    __syncthreads();
    for (int off = 1; off < SCAN_T; off <<= 1) {
        int x = (t >= off) ? sdata[t - off] : 0;
        __syncthreads();
        sdata[t] += x;
        __syncthreads();
    }
    int tbase = (t > 0) ? sdata[t - 1] : 0;
#pragma unroll
    for (int j = 0; j < 8; ++j) {
        int i = base_i + j;
        if (i < n) offsets[i + 1] = tbase + vals[j];
    }
    if (t == SCAN_T - 1) bsum[blockIdx.x] = sdata[SCAN_T - 1];
}

__global__ void scan2_kernel(int* __restrict__ bsum, int nb) {
    if (threadIdx.x == 0 && blockIdx.x == 0) {
        int run = 0;
        for (int i = 0; i < nb; ++i) { int v = bsum[i]; bsum[i] = run; run += v; }
    }
}

__global__ void scan3_kernel(int* __restrict__ offsets,
                             const int* __restrict__ bsum, int n) {
    int i = blockIdx.x * blockDim.x + threadIdx.x;
    if (i == 0) offsets[0] = 0;
    if (i < n) offsets[i + 1] += bsum[i / SCAN_CHUNK];
}

// counting-sort scatter; packs (col, val-bits) into one int2 stream
__global__ void scatter_kernel(const int* __restrict__ rows,
                               const int* __restrict__ cols,
                               const float* __restrict__ vals, int nnz,
                               const int* __restrict__ offsets,
                               int* __restrict__ counts,
                               int2* __restrict__ edges) {
    int e = blockIdx.x * blockDim.x + threadIdx.x;
    if (e < nnz) {
        int r = rows[e];
        int p = offsets[r] + atomicSub(&counts[r], 1) - 1;
        edges[p] = make_int2(cols[e], __float_as_int(vals[e]));
    }
}

__device__ __forceinline__ float bf_lo(unsigned u) {
    return __uint_as_float(u << 16);
}
__device__ __forceinline__ float bf_hi(unsigned u) {
    return __uint_as_float(u & 0xffff0000u);
}

#define FMA8(u, v)                                                  \
    do {                                                            \
        const float _v = (v);                                       \
        a0 += _v * bf_lo((u).x); a1 += _v * bf_hi((u).x);           \
        a2 += _v * bf_lo((u).y); a3 += _v * bf_hi((u).y);           \
        a4 += _v * bf_lo((u).z); a5 += _v * bf_hi((u).z);           \
        a6 += _v * bf_lo((u).w); a7 += _v * bf_hi((u).w);           \
    } while (0)

// wave-per-row spmm: block = 256 threads = 4 waves = 4 rows; lane covers
// 8 batch elems via one 16-B bf16x8 gather per edge. No barriers.
// R4: 4-deep gather groups, next edge group prefetched one group ahead.
__global__ __launch_bounds__(256) void spmm_kernel(
        const ushort* __restrict__ xT,       // bf16 (IN, B)
        const int* __restrict__ offsets,     // OUT+1
        const int2* __restrict__ edges,      // (col, val-bits), row-sorted
        const float* __restrict__ bias,      // OUT
        float* __restrict__ y,               // (OUT, B) fp32
        int B, int OUTn) {
    const int lane = threadIdx.x & 63;
    const int r = blockIdx.x * 4 + (threadIdx.x >> 6);
    if (r >= OUTn) return;
    const int e0 = offsets[r];
    const int e1 = offsets[r + 1];
    const float bv = bias[r];
    const ushort* xb = xT + (size_t)(lane << 3);   // 8 batch per lane

    float a0 = 0.f, a1 = 0.f, a2 = 0.f, a3 = 0.f;
    float a4 = 0.f, a5 = 0.f, a6 = 0.f, a7 = 0.f;

    int e = e0;
    const int nfull = (e1 - e0) >> 2;
    if (nfull > 0) {
        int2 d0 = edges[e + 0], d1 = edges[e + 1];
        int2 d2 = edges[e + 2], d3 = edges[e + 3];
        for (int g = 1; g < nfull; ++g) {
            const int2 n0 = edges[e + 4], n1 = edges[e + 5];
            const int2 n2 = edges[e + 6], n3 = edges[e + 7];
            const uint4 u0 = *(const uint4*)(xb + (size_t)d0.x * B);
            const uint4 u1 = *(const uint4*)(xb + (size_t)d1.x * B);
            const uint4 u2 = *(const uint4*)(xb + (size_t)d2.x * B);
            const uint4 u3 = *(const uint4*)(xb + (size_t)d3.x * B);
            FMA8(u0, __int_as_float(d0.y));
            FMA8(u1, __int_as_float(d1.y));
            FMA8(u2, __int_as_float(d2.y));
            FMA8(u3, __int_as_float(d3.y));
            d0 = n0; d1 = n1; d2 = n2; d3 = n3;
            e += 4;
        }
        {   // last full group
            const uint4 u0 = *(const uint4*)(xb + (size_t)d0.x * B);
            const uint4 u1 = *(const uint4*)(xb + (size_t)d1.x * B);
            const uint4 u2 = *(const uint4*)(xb + (size_t)d2.x * B);
            const uint4 u3 = *(const uint4*)(xb + (size_t)d3.x * B);
            FMA8(u0, __int_as_float(d0.y));
            FMA8(u1, __int_as_float(d1.y));
            FMA8(u2, __int_as_float(d2.y));
            FMA8(u3, __int_as_float(d3.y));
            e += 4;
        }
    }
    for (; e < e1; ++e) {
        const int2 d = edges[e];
        const uint4 u = *(const uint4*)(xb + (size_t)d.x * B);
        FMA8(u, __int_as_float(d.y));
    }

    float* yp = y + (size_t)r * B + (size_t)(lane << 3);
    *(float4*)(yp)     = make_float4(a0 + bv, a1 + bv, a2 + bv, a3 + bv);
    *(float4*)(yp + 4) = make_float4(a4 + bv, a5 + bv, a6 + bv, a7 + bv);
}

extern "C" void kernel_launch(void* const* d_in, const int* in_sizes, int n_in,
                              void* d_out, int out_size, void* d_ws, size_t ws_size,
                              hipStream_t stream) {
    const float* x       = (const float*)d_in[0];   // (B, IN)
    const int*   indices = (const int*)  d_in[1];   // [2, NNZ]
    const float* values  = (const float*)d_in[2];   // NNZ
    const float* bias    = (const float*)d_in[3];   // OUT

    float* out = (float*)d_out;

    const int NNZ = in_sizes[2];
    const int OUT = in_sizes[3];
    const int B   = out_size / OUT;
    const int IN  = (int)((size_t)in_sizes[0] / (size_t)B);

    const int* rows = indices;
    const int* cols = indices + NNZ;

    // workspace layout (section sizes are 16B multiples for the shapes in play)
    char* ws = (char*)d_ws;
    __hip_bfloat16* xT = (__hip_bfloat16*)ws;  ws += (size_t)IN * B * sizeof(__hip_bfloat16);
    float* y       = (float*)ws;  ws += (size_t)OUT * B * sizeof(float);
    int2*  edges   = (int2*)ws;   ws += (size_t)NNZ * sizeof(int2);
    int*   counts  = (int*)ws;    ws += (size_t)OUT * sizeof(int);
    int*   offsets = (int*)ws;    ws += (size_t)(OUT + 1) * sizeof(int);
    int*   bsum    = (int*)ws;    ws += 256 * sizeof(int);

    const int nchunks = (OUT + SCAN_CHUNK - 1) / SCAN_CHUNK;

    // 1) x (B,IN) fp32 -> xT (IN,B) bf16 (vectorized 64x64 transpose)
    transpose_bf16_v2<<<dim3((IN + 63) / 64, (B + 63) / 64), 256, 0, stream>>>(
        x, xT, B, IN);

    // 2) CSR build: histogram -> hierarchical scan -> packed scatter
    zero_i32_kernel<<<(OUT + 255) / 256, 256, 0, stream>>>(counts, OUT);
    hist_kernel<<<(NNZ + 255) / 256, 256, 0, stream>>>(rows, NNZ, counts);
    scan1_kernel<<<nchunks, SCAN_T, 0, stream>>>(counts, offsets, bsum, OUT);
    scan2_kernel<<<1, 64, 0, stream>>>(bsum, nchunks);
    scan3_kernel<<<(OUT + 255) / 256, 256, 0, stream>>>(offsets, bsum, OUT);
    scatter_kernel<<<(NNZ + 255) / 256, 256, 0, stream>>>(
        rows, cols, values, NNZ, offsets, counts, edges);

    // 3) heavy phase: wave-per-row, 4-deep bf16x8 gather pipeline
    spmm_kernel<<<(OUT + 3) / 4, 256, 0, stream>>>(
        (const ushort*)xT, offsets, edges, bias, y, B, OUT);

    // 4) y (OUT,B) -> out (B,OUT) (vectorized 64x64 transpose)
    transpose32_v2<<<dim3((B + 63) / 64, (OUT + 63) / 64), 256, 0, stream>>>(
        y, out, OUT, B);
}